// Round 9
// baseline (149.182 us; speedup 1.0000x reference)
//
#include <hip/hip_runtime.h>
#include <hip/hip_fp16.h>
#include <stdint.h>

#define IN_F 8192
#define OUT_F 8192
#define NGROUPS 64
#define QW_COLS 1024   // IN_F/8 packed int32 per output row
#define QZ_COLS 8
#define M_TOTAL 128
#define BN 128
#define KSPLIT 16
#define KRANGE (IN_F / KSPLIT)  // 512
#define BK 32
#define NITER (KRANGE / BK)     // 16
#define NTILES (OUT_F / BN)     // 64
#define K16S (IN_F / 16)        // 512

typedef _Float16 half8 __attribute__((ext_vector_type(8)));
typedef float floatx16 __attribute__((ext_vector_type(16)));

typedef __attribute__((address_space(3))) uint32_t* lds_u32p;
typedef const __attribute__((address_space(1))) uint32_t* glb_u32p;

// async 16B/lane global->LDS; LDS dest = uniform base + lane*16
__device__ inline void gl_lds16(const uint16_t* g, uint16_t* l) {
  __builtin_amdgcn_global_load_lds((glb_u32p)g, (lds_u32p)l, 16, 0, 0);
}

// Dequant one packed word (8 nibbles) -> 8 f16 in k-order, bit-identical to ref.
__device__ inline uint4 dq_word(uint32_t w, uint32_t hz2u, uint32_t s2u) {
  const __half2 hz2 = __builtin_bit_cast(__half2, hz2u);
  const __half2 s2 = __builtin_bit_cast(__half2, s2u);
  uint32_t r[4];
#pragma unroll
  for (int p = 0; p < 4; ++p) {
    uint32_t t = ((w >> (4 * p)) & 0x000F000Fu) | 0x64006400u;
    __half2 v = __hmul2(__hsub2(__builtin_bit_cast(__half2, t), hz2), s2);
    r[p] = __builtin_bit_cast(uint32_t, v);  // (elem p, elem p+4)
  }
  uint4 o;
  o.x = (r[0] & 0xFFFFu) | (r[1] << 16);
  o.y = (r[2] & 0xFFFFu) | (r[3] << 16);
  o.z = (r[0] >> 16) | (r[1] & 0xFFFF0000u);
  o.w = (r[2] >> 16) | (r[3] & 0xFFFF0000u);
  return o;
}

// dequant this thread's 2 words (k-span 16 of BK=32) into B fragment buffer.
// dst0 = chunk base for (nblk, ks=wh) at lane l31c; word i -> half i (offset i*32 lanes)
__device__ inline void dq2_to_lds(uint2 q, float sf, uint32_t z, uint16_t* dst0) {
  const uint32_t hz2u = 0x64006400u | z | (z << 16);
  const uint16_t hs = __builtin_bit_cast(uint16_t, __float2half(sf));
  const uint32_t s2u = (uint32_t)hs | ((uint32_t)hs << 16);
  *(uint4*)(dst0) = dq_word(q.x, hz2u, s2u);
  *(uint4*)(dst0 + 32 * 8) = dq_word(q.y, hz2u, s2u);
}

__global__ __launch_bounds__(256, 4) void awq_fast(
    const uint16_t* __restrict__ aT, const int* __restrict__ qweight,
    const float* __restrict__ scales, const int* __restrict__ qzeros,
    float* __restrict__ out) {
  // fragment-major double buffers: chunk (blk*2 + k16) -> 64 lanes x 8 halves
  __shared__ uint16_t aL[2][8 * 512];  // 2 x 8 KiB
  __shared__ uint16_t bL[2][8 * 512];  // 2 x 8 KiB

  const int tid = threadIdx.x;
  const int bx = blockIdx.x;
  const int ntile = bx & (NTILES - 1);
  const int kslice = bx >> 6;          // 0..15
  const int n0 = ntile * BN;

  const int lane = tid & 63;
  const int wave = tid >> 6;
  const int mw = wave >> 1;  // 2x2 waves; wave tile 64x64 (2m x 2n acc)
  const int nw = wave & 1;
  const int l31 = lane & 31;
  const int half = lane >> 5;

  floatx16 acc[2][2] = {};

  // dequant role: col = n0 + (tid>>1); wh = tid&1 selects ks half of BK=32
  const int wcol = tid >> 1;
  const int wh = tid & 1;
  const long long col = n0 + wcol;
  const long long wbase = col * QW_COLS + kslice * 64 + wh * 2;
  const int bOff = (((wcol >> 5) * 2 + wh) * 64 + (wcol & 31)) * 8;

  // this kslice covers groups kslice*4 .. +3 (GROUP=128, KRANGE=512)
  const float4 s4 = *(const float4*)(scales + col * NGROUPS + kslice * 4);
  const float sarr[4] = {s4.x, s4.y, s4.z, s4.w};
  const uint32_t zword = (uint32_t)qzeros[col * QZ_COLS + (kslice >> 1)];
  const int zsh = (kslice & 1) * 16;  // bit offset of group kslice*4 in zword

  // qweight pipeline: slots hold q[it+1..it+3] (i%3) at top of iter it
  uint2 q0 = *(const uint2*)(qweight + wbase);           // q[0]
  uint2 qs[3];
  qs[1] = *(const uint2*)(qweight + wbase + 4);          // q[1] -> slot 1
  qs[2] = *(const uint2*)(qweight + wbase + 8);          // q[2] -> slot 2
  qs[0] = *(const uint2*)(qweight + wbase + 12);         // q[3] -> slot 0

  // pre-loop: stage A(0) + dequant q[0] into buf 0
  {
#pragma unroll
    for (int k16r = 0; k16r < 2; ++k16r)
      gl_lds16(aT + (((long long)wave * K16S + kslice * 32 + k16r) * 64 + lane) * 8,
               &aL[0][(wave * 2 + k16r) * 512]);
    dq2_to_lds(q0, sarr[0], (zword >> zsh) & 0xFu, &bL[0][bOff]);
  }

#pragma unroll
  for (int it = 0; it < NITER; ++it) {
    const int pb = it & 1;
    const int pn = pb ^ 1;
    __syncthreads();  // drains buf[pb] A-DMAs (vmcnt) + B ds_writes (lgkm)

    if (it + 1 < NITER) {
      // async A-stage for it+1 (flies under this iter's MFMA)
#pragma unroll
      for (int k16r = 0; k16r < 2; ++k16r)
        gl_lds16(aT + (((long long)wave * K16S + kslice * 32 + (it + 1) * 2 + k16r) *
                           64 + lane) * 8,
                 &aL[pn][(wave * 2 + k16r) * 512]);
      // dequant q[it+1] -> buf pn
      const int gidx = (it + 1) >> 2;  // group within slice
      const uint32_t z = (zword >> (zsh + gidx * 4)) & 0xFu;
      dq2_to_lds(qs[(it + 1) % 3], sarr[gidx], z, &bL[pn][bOff]);
      // refill consumed slot with q[it+4]
      if (it + 4 < NITER)
        qs[(it + 1) % 3] = *(const uint2*)(qweight + wbase + (it + 4) * 4);
    }

    // MFMA phase on buf pb: 2 k16-steps x (2 mblk x 2 nblk)
#pragma unroll
    for (int ks = 0; ks < 2; ++ks) {
      half8 a0 = *(const half8*)(&aL[pb][((2 * mw) * 2 + ks) * 512 + lane * 8]);
      half8 a1 = *(const half8*)(&aL[pb][((2 * mw + 1) * 2 + ks) * 512 + lane * 8]);
      half8 b0 = *(const half8*)(&bL[pb][((2 * nw) * 2 + ks) * 512 + lane * 8]);
      half8 b1 = *(const half8*)(&bL[pb][((2 * nw + 1) * 2 + ks) * 512 + lane * 8]);
      acc[0][0] = __builtin_amdgcn_mfma_f32_32x32x16_f16(a0, b0, acc[0][0], 0, 0, 0);
      acc[0][1] = __builtin_amdgcn_mfma_f32_32x32x16_f16(a0, b1, acc[0][1], 0, 0, 0);
      acc[1][0] = __builtin_amdgcn_mfma_f32_32x32x16_f16(a1, b0, acc[1][0], 0, 0, 0);
      acc[1][1] = __builtin_amdgcn_mfma_f32_32x32x16_f16(a1, b1, acc[1][1], 0, 0, 0);
    }
  }

  // epilogue: K-split partials into bias-pre-initialized out (device atomics).
  // C/D 32x32: col=lane&31, row=(reg&3)+8*(reg>>2)+4*(lane>>5)
#pragma unroll
  for (int im = 0; im < 2; ++im)
#pragma unroll
    for (int in2 = 0; in2 < 2; ++in2) {
      const int n = n0 + (2 * nw + in2) * 32 + l31;
#pragma unroll
      for (int reg = 0; reg < 16; ++reg) {
        const int m = (2 * mw + im) * 32 + (reg & 3) + 8 * (reg >> 2) + 4 * half;
        atomicAdd(out + (long long)m * OUT_F + n, acc[im][in2][reg]);
      }
    }
}

// prologue: aT = f16(x) fragment-major:
// aT[mblk][k16][hf*32+l31][j] = x[mblk*32 + l31][k16*16 + hf*8 + j]
__global__ __launch_bounds__(256) void prologue(const float* __restrict__ x,
                                                uint16_t* __restrict__ aT) {
  const int t = blockIdx.x * 256 + threadIdx.x;
  const int idx = t * 8;
  const int row = idx >> 13;
  const int col = idx & (IN_F - 1);

  float4 v0 = *(const float4*)(x + idx);
  float4 v1 = *(const float4*)(x + idx + 4);
  union { uint16_t h[8]; uint4 v; } r;
  r.h[0] = __builtin_bit_cast(uint16_t, __float2half(v0.x));
  r.h[1] = __builtin_bit_cast(uint16_t, __float2half(v0.y));
  r.h[2] = __builtin_bit_cast(uint16_t, __float2half(v0.z));
  r.h[3] = __builtin_bit_cast(uint16_t, __float2half(v0.w));
  r.h[4] = __builtin_bit_cast(uint16_t, __float2half(v1.x));
  r.h[5] = __builtin_bit_cast(uint16_t, __float2half(v1.y));
  r.h[6] = __builtin_bit_cast(uint16_t, __float2half(v1.z));
  r.h[7] = __builtin_bit_cast(uint16_t, __float2half(v1.w));

  const int mblk = row >> 5;
  const int l31r = row & 31;
  const int k16 = col >> 4;
  const int hf = (col >> 3) & 1;
  const long long dst = (((long long)mblk * K16S + k16) * 64 + hf * 32 + l31r) * 8;
  *(uint4*)(aT + dst) = r.v;
}

__global__ __launch_bounds__(256) void init_out(const float* __restrict__ bias,
                                                float* __restrict__ out) {
  int idx = (blockIdx.x * 256 + threadIdx.x) * 4;
  float4 b = *(const float4*)(bias + (idx & (OUT_F - 1)));
  *(float4*)(out + idx) = b;
}

// low fallback (no workspace): f32 x reads, single-buffer LDS, atomics.
// Own geometry: 8 K-slices of 1024, BK=128, 8 iters.
__global__ __launch_bounds__(256) void awq_fallback(
    const float* __restrict__ xf32, const int* __restrict__ qweight,
    const float* __restrict__ scales, const int* __restrict__ qzeros,
    float* __restrict__ out) {
  __shared__ uint16_t bT[4 * 8 * 64 * 8];  // 32 KiB

  const int tid = threadIdx.x;
  const int bx = blockIdx.x;
  const int ntile = bx & (NTILES - 1);
  const int kslice = bx >> 6;  // 0..7
  const int n0 = ntile * BN;
  const int kbase = kslice * 1024;

  const int lane = tid & 63;
  const int wave = tid >> 6;
  const int mw = wave >> 1;
  const int nw = wave & 1;
  const int l31 = lane & 31;
  const int half = lane >> 5;

  floatx16 acc[2][2] = {};

  const int wcol = tid >> 1;
  const int wh = tid & 1;
  const long long qw_base = (long long)(n0 + wcol) * QW_COLS + (kbase >> 3) + wh * 8;
  const long long sc_base = (long long)(n0 + wcol) * NGROUPS;
  const long long qz_base = (long long)(n0 + wcol) * QZ_COLS;
  const int bOff = ((wcol >> 5) * 8 * 64 + (wcol & 31)) * 8;

  const long long arow0 = (long long)(mw * 64 + l31) * IN_F + half * 8;
  const long long arow1 = (long long)(mw * 64 + 32 + l31) * IN_F + half * 8;

  for (int it = 0; it < 8; ++it) {
    const int g = kslice * 8 + it;
    const float sf = scales[sc_base + g];
    const int zw = qzeros[qz_base + (g >> 3)];
    const uint32_t z = (uint32_t)(zw >> ((g & 7) * 4)) & 0xFu;
    const uint32_t hz2u = 0x64006400u | z | (z << 16);
    const uint16_t hs = __builtin_bit_cast(uint16_t, __float2half(sf));
    const uint32_t s2u = (uint32_t)hs | ((uint32_t)hs << 16);
    uint4 q0 = *(const uint4*)(qweight + qw_base + it * 16);
    uint4 q1 = *(const uint4*)(qweight + qw_base + it * 16 + 4);

    if (it > 0) __syncthreads();
    const uint32_t w[8] = {q0.x, q0.y, q0.z, q0.w, q1.x, q1.y, q1.z, q1.w};
#pragma unroll
    for (int i = 0; i < 8; ++i) {
      uint4 v = dq_word(w[i], hz2u, s2u);
      *(uint4*)(&bT[bOff + (((wh * 4 + (i >> 1)) * 64 + (i & 1) * 32) * 8)]) = v;
    }
    __syncthreads();

#pragma unroll
    for (int ks = 0; ks < 8; ++ks) {
      const int ko = kbase + it * 128 + ks * 16;
      float4 f0 = *(const float4*)(xf32 + arow0 + ko);
      float4 f1 = *(const float4*)(xf32 + arow0 + ko + 4);
      half8 a0 = half8{(_Float16)f0.x, (_Float16)f0.y, (_Float16)f0.z, (_Float16)f0.w,
                       (_Float16)f1.x, (_Float16)f1.y, (_Float16)f1.z, (_Float16)f1.w};
      float4 g0 = *(const float4*)(xf32 + arow1 + ko);
      float4 g1 = *(const float4*)(xf32 + arow1 + ko + 4);
      half8 a1 = half8{(_Float16)g0.x, (_Float16)g0.y, (_Float16)g0.z, (_Float16)g0.w,
                       (_Float16)g1.x, (_Float16)g1.y, (_Float16)g1.z, (_Float16)g1.w};
      half8 b0 = *(const half8*)(&bT[((nw * 2) * 8 * 64 + ks * 64 + lane) * 8]);
      half8 b1 = *(const half8*)(&bT[((nw * 2 + 1) * 8 * 64 + ks * 64 + lane) * 8]);
      acc[0][0] = __builtin_amdgcn_mfma_f32_32x32x16_f16(a0, b0, acc[0][0], 0, 0, 0);
      acc[0][1] = __builtin_amdgcn_mfma_f32_32x32x16_f16(a0, b1, acc[0][1], 0, 0, 0);
      acc[1][0] = __builtin_amdgcn_mfma_f32_32x32x16_f16(a1, b0, acc[1][0], 0, 0, 0);
      acc[1][1] = __builtin_amdgcn_mfma_f32_32x32x16_f16(a1, b1, acc[1][1], 0, 0, 0);
    }
  }

  const int cn = n0 + nw * 64 + l31;
#pragma unroll
  for (int im = 0; im < 2; ++im)
#pragma unroll
    for (int in2 = 0; in2 < 2; ++in2)
#pragma unroll
      for (int reg = 0; reg < 16; ++reg) {
        int m = mw * 64 + im * 32 + (reg & 3) + 8 * (reg >> 2) + 4 * half;
        atomicAdd(out + (long long)m * OUT_F + cn + in2 * 32, acc[im][in2][reg]);
      }
}

extern "C" void kernel_launch(void* const* d_in, const int* in_sizes, int n_in,
                              void* d_out, int out_size, void* d_ws, size_t ws_size,
                              hipStream_t stream) {
  const float* x = (const float*)d_in[0];
  const int* qw = (const int*)d_in[1];
  const float* sc = (const float*)d_in[2];
  const int* qz = (const int*)d_in[3];
  const float* bias = (const float*)d_in[4];
  float* out = (float*)d_out;
  uint16_t* aT = (uint16_t*)d_ws;

  const size_t aT_bytes = (size_t)M_TOTAL * IN_F * sizeof(uint16_t);  // 2 MiB
  init_out<<<(M_TOTAL * OUT_F) / (256 * 4), 256, 0, stream>>>(bias, out);
  if (ws_size >= aT_bytes) {
    prologue<<<(M_TOTAL * IN_F) / (256 * 8), 256, 0, stream>>>(x, aT);
    awq_fast<<<NTILES * KSPLIT, 256, 0, stream>>>(aT, qw, sc, qz, out);
  } else {
    awq_fallback<<<NTILES * 8, 256, 0, stream>>>(x, qw, sc, qz, out);
  }
}

// Round 10
// 112.444 us; speedup vs baseline: 1.3267x; 1.3267x over previous
//
#include <hip/hip_runtime.h>
#include <hip/hip_fp16.h>
#include <stdint.h>

#define IN_F 8192
#define OUT_F 8192
#define NGROUPS 64
#define QW_COLS 1024   // IN_F/8 packed int32 per output row
#define QZ_COLS 8
#define M_TOTAL 128
#define BN 256
#define KSPLIT 8
#define KRANGE (IN_F / KSPLIT)  // 1024
#define BK 64
#define NITER (KRANGE / BK)     // 16
#define NTILES (OUT_F / BN)     // 32
#define K16S (IN_F / 16)        // 512

typedef _Float16 half8 __attribute__((ext_vector_type(8)));
typedef float floatx16 __attribute__((ext_vector_type(16)));

typedef __attribute__((address_space(3))) uint32_t* lds_u32p;
typedef const __attribute__((address_space(1))) uint32_t* glb_u32p;

// async 16B/lane global->LDS; LDS dest = uniform base + lane*16
__device__ inline void gl_lds16(const uint16_t* g, uint16_t* l) {
  __builtin_amdgcn_global_load_lds((glb_u32p)g, (lds_u32p)l, 16, 0, 0);
}

// Dequant one packed word (8 nibbles) -> 8 f16 in k-order, bit-identical to ref.
__device__ inline uint4 dq_word(uint32_t w, uint32_t hz2u, uint32_t s2u) {
  const __half2 hz2 = __builtin_bit_cast(__half2, hz2u);
  const __half2 s2 = __builtin_bit_cast(__half2, s2u);
  uint32_t r[4];
#pragma unroll
  for (int p = 0; p < 4; ++p) {
    uint32_t t = ((w >> (4 * p)) & 0x000F000Fu) | 0x64006400u;
    __half2 v = __hmul2(__hsub2(__builtin_bit_cast(__half2, t), hz2), s2);
    r[p] = __builtin_bit_cast(uint32_t, v);  // (elem p, elem p+4)
  }
  uint4 o;
  o.x = (r[0] & 0xFFFFu) | (r[1] << 16);
  o.y = (r[2] & 0xFFFFu) | (r[3] << 16);
  o.z = (r[0] >> 16) | (r[1] & 0xFFFF0000u);
  o.w = (r[2] >> 16) | (r[3] & 0xFFFF0000u);
  return o;
}

// dequant this thread's 4 words (k-span 32 of BK=64) into B fragment buffer.
// word i -> ks = wh*2 + (i>>1), hf = i&1 (verified R8 mapping)
__device__ inline void dq4_to_lds(uint4 q, float sf, uint32_t z, uint16_t* bbuf,
                                  int bOff, int wh) {
  const uint32_t hz2u = 0x64006400u | z | (z << 16);
  const uint16_t hs = __builtin_bit_cast(uint16_t, __float2half(sf));
  const uint32_t s2u = (uint32_t)hs | ((uint32_t)hs << 16);
  const uint32_t w[4] = {q.x, q.y, q.z, q.w};
#pragma unroll
  for (int i = 0; i < 4; ++i) {
    uint4 v = dq_word(w[i], hz2u, s2u);
    *(uint4*)(bbuf + bOff + (((wh * 2 + (i >> 1)) * 64 + (i & 1) * 32) * 8)) = v;
  }
}

// EPI 0: streaming stores to per-kslice partial buffer (reduce kernel finishes).
// EPI 1: atomicAdd into bias-pre-initialized out.
template <int EPI>
__global__ __launch_bounds__(512, 2) void awq_fast(
    const uint16_t* __restrict__ aT, const int* __restrict__ qweight,
    const float* __restrict__ scales, const int* __restrict__ qzeros,
    float* __restrict__ part, float* __restrict__ out) {
  // fragment-major double buffers: chunk -> 64 lanes x 8 halves (1 KiB)
  __shared__ uint16_t aL[2][16 * 512];  // A: 4 mblk x 4 k16 = 16 KiB per buf
  __shared__ uint16_t bL[2][32 * 512];  // B: 8 nblk x 4 ks  = 32 KiB per buf

  const int tid = threadIdx.x;
  const int bx = blockIdx.x;
  const int ntile = bx & (NTILES - 1);
  const int kslice = bx >> 5;          // 0..7
  const int n0 = ntile * BN;

  const int lane = tid & 63;
  const int wave = tid >> 6;           // 0..7
  const int mw = wave >> 2;            // 2 m-waves x 4 n-waves; wave tile 64x64
  const int nw = wave & 3;
  const int l31 = lane & 31;
  const int half = lane >> 5;

  floatx16 acc[2][2] = {};

  // dequant role: col = n0 + (tid>>1); wh = tid&1 selects k-half (32) of BK=64
  const int wcol = tid >> 1;
  const int wh = tid & 1;
  const long long col = n0 + wcol;
  const long long wbase = col * QW_COLS + kslice * 128 + wh * 4;
  const int bOff = (((wcol >> 5) * 4) * 64 + (wcol & 31)) * 8;

  // this kslice covers groups kslice*8 .. +7 == exactly one qzeros word
  const float4 sA = *(const float4*)(scales + col * NGROUPS + kslice * 8);
  const float4 sB = *(const float4*)(scales + col * NGROUPS + kslice * 8 + 4);
  const float sarr[8] = {sA.x, sA.y, sA.z, sA.w, sB.x, sB.y, sB.z, sB.w};
  const uint32_t zword = (uint32_t)qzeros[col * QZ_COLS + kslice];

  // qweight register pipeline, distance 2: q[it] = uint4 at wbase + it*8
  uint4 q0 = *(const uint4*)(qweight + wbase);        // q[0]
  uint4 qs[2];
  qs[1] = *(const uint4*)(qweight + wbase + 8);       // q[1]
  qs[0] = *(const uint4*)(qweight + wbase + 16);      // q[2]

  // A staging: 16 chunks (mblk*4 + k16r); wave stages chunks 2w, 2w+1
  const int c0 = 2 * wave;

  // pre-loop: stage A(0) + dequant q[0] into buf 0
  {
#pragma unroll
    for (int i = 0; i < 2; ++i) {
      const int c = c0 + i;
      gl_lds16(aT + (((long long)(c >> 2) * K16S + kslice * 64 + (c & 3)) * 64 + lane) * 8,
               &aL[0][c * 512]);
    }
    dq4_to_lds(q0, sarr[0], zword & 0xFu, bL[0], bOff, wh);
  }

#pragma unroll
  for (int it = 0; it < NITER; ++it) {
    const int pb = it & 1;
    const int pn = pb ^ 1;
    __syncthreads();  // drains buf[pb] A-DMAs (vmcnt) + B ds_writes (lgkm)

    if (it + 1 < NITER) {
      // async A-stage for it+1 (flies under this iter's MFMA)
#pragma unroll
      for (int i = 0; i < 2; ++i) {
        const int c = c0 + i;
        gl_lds16(aT + (((long long)(c >> 2) * K16S + kslice * 64 + (it + 1) * 4 +
                        (c & 3)) * 64 + lane) * 8,
                 &aL[pn][c * 512]);
      }
      // dequant q[it+1] -> buf pn
      const int gl = (it + 1) >> 1;  // group within slice (BK=64, GROUP=128)
      const uint32_t z = (zword >> (gl * 4)) & 0xFu;
      dq4_to_lds(qs[(it + 1) & 1], sarr[gl], z, bL[pn], bOff, wh);
      // refill consumed slot with q[it+3]
      if (it + 3 < NITER)
        qs[(it + 1) & 1] = *(const uint4*)(qweight + wbase + (it + 3) * 8);
    }

    // MFMA phase on buf pb: 4 k16-steps x (2 mblk x 2 nblk)
#pragma unroll
    for (int ks = 0; ks < 4; ++ks) {
      half8 a0 = *(const half8*)(&aL[pb][((2 * mw) * 4 + ks) * 512 + lane * 8]);
      half8 a1 = *(const half8*)(&aL[pb][((2 * mw + 1) * 4 + ks) * 512 + lane * 8]);
      half8 b0 = *(const half8*)(&bL[pb][((2 * nw) * 4 + ks) * 512 + lane * 8]);
      half8 b1 = *(const half8*)(&bL[pb][((2 * nw + 1) * 4 + ks) * 512 + lane * 8]);
      acc[0][0] = __builtin_amdgcn_mfma_f32_32x32x16_f16(a0, b0, acc[0][0], 0, 0, 0);
      acc[0][1] = __builtin_amdgcn_mfma_f32_32x32x16_f16(a0, b1, acc[0][1], 0, 0, 0);
      acc[1][0] = __builtin_amdgcn_mfma_f32_32x32x16_f16(a1, b0, acc[1][0], 0, 0, 0);
      acc[1][1] = __builtin_amdgcn_mfma_f32_32x32x16_f16(a1, b1, acc[1][1], 0, 0, 0);
    }
  }

  // epilogue. C/D 32x32: col=lane&31, row=(reg&3)+8*(reg>>2)+4*(lane>>5)
#pragma unroll
  for (int im = 0; im < 2; ++im)
#pragma unroll
    for (int in2 = 0; in2 < 2; ++in2) {
      const int n = n0 + (2 * nw + in2) * 32 + l31;
#pragma unroll
      for (int reg = 0; reg < 16; ++reg) {
        const int m = (2 * mw + im) * 32 + (reg & 3) + 8 * (reg >> 2) + 4 * half;
        if (EPI == 0) {
          part[((long long)kslice * M_TOTAL + m) * OUT_F + n] = acc[im][in2][reg];
        } else {
          atomicAdd(out + (long long)m * OUT_F + n, acc[im][in2][reg]);
        }
      }
    }
}

// reduce: out = bias + sum over KSPLIT partials
__global__ __launch_bounds__(256) void reduce_out(const float* __restrict__ part,
                                                  const float* __restrict__ bias,
                                                  float* __restrict__ out) {
  const long long idx = ((long long)blockIdx.x * 256 + threadIdx.x) * 4;
  float4 s = *(const float4*)(bias + (idx & (OUT_F - 1)));
#pragma unroll
  for (int k = 0; k < KSPLIT; ++k) {
    float4 p = *(const float4*)(part + (long long)k * M_TOTAL * OUT_F + idx);
    s.x += p.x; s.y += p.y; s.z += p.z; s.w += p.w;
  }
  *(float4*)(out + idx) = s;
}

// prologue: aT = f16(x) fragment-major:
// aT[mblk][k16][hf*32+l31][j] = x[mblk*32 + l31][k16*16 + hf*8 + j]
__global__ __launch_bounds__(256) void prologue(const float* __restrict__ x,
                                                uint16_t* __restrict__ aT) {
  const int t = blockIdx.x * 256 + threadIdx.x;
  const int idx = t * 8;
  const int row = idx >> 13;
  const int col = idx & (IN_F - 1);

  float4 v0 = *(const float4*)(x + idx);
  float4 v1 = *(const float4*)(x + idx + 4);
  union { uint16_t h[8]; uint4 v; } r;
  r.h[0] = __builtin_bit_cast(uint16_t, __float2half(v0.x));
  r.h[1] = __builtin_bit_cast(uint16_t, __float2half(v0.y));
  r.h[2] = __builtin_bit_cast(uint16_t, __float2half(v0.z));
  r.h[3] = __builtin_bit_cast(uint16_t, __float2half(v0.w));
  r.h[4] = __builtin_bit_cast(uint16_t, __float2half(v1.x));
  r.h[5] = __builtin_bit_cast(uint16_t, __float2half(v1.y));
  r.h[6] = __builtin_bit_cast(uint16_t, __float2half(v1.z));
  r.h[7] = __builtin_bit_cast(uint16_t, __float2half(v1.w));

  const int mblk = row >> 5;
  const int l31r = row & 31;
  const int k16 = col >> 4;
  const int hf = (col >> 3) & 1;
  const long long dst = (((long long)mblk * K16S + k16) * 64 + hf * 32 + l31r) * 8;
  *(uint4*)(aT + dst) = r.v;
}

__global__ __launch_bounds__(256) void init_out(const float* __restrict__ bias,
                                                float* __restrict__ out) {
  int idx = (blockIdx.x * 256 + threadIdx.x) * 4;
  float4 b = *(const float4*)(bias + (idx & (OUT_F - 1)));
  *(float4*)(out + idx) = b;
}

// low fallback (no workspace): f32 x reads, single-buffer LDS, atomics.
// BN=128 geometry, 8 K-slices of 1024, BK=128, 8 iters.
#define FB_NTILES 64
__global__ __launch_bounds__(256) void awq_fallback(
    const float* __restrict__ xf32, const int* __restrict__ qweight,
    const float* __restrict__ scales, const int* __restrict__ qzeros,
    float* __restrict__ out) {
  __shared__ uint16_t bT[4 * 8 * 64 * 8];  // 32 KiB

  const int tid = threadIdx.x;
  const int bx = blockIdx.x;
  const int ntile = bx & (FB_NTILES - 1);
  const int kslice = bx >> 6;  // 0..7
  const int n0 = ntile * 128;
  const int kbase = kslice * 1024;

  const int lane = tid & 63;
  const int wave = tid >> 6;
  const int mw = wave >> 1;
  const int nw = wave & 1;
  const int l31 = lane & 31;
  const int half = lane >> 5;

  floatx16 acc[2][2] = {};

  const int wcol = tid >> 1;
  const int wh = tid & 1;
  const long long qw_base = (long long)(n0 + wcol) * QW_COLS + (kbase >> 3) + wh * 8;
  const long long sc_base = (long long)(n0 + wcol) * NGROUPS;
  const long long qz_base = (long long)(n0 + wcol) * QZ_COLS;
  const int bOff = ((wcol >> 5) * 8 * 64 + (wcol & 31)) * 8;

  const long long arow0 = (long long)(mw * 64 + l31) * IN_F + half * 8;
  const long long arow1 = (long long)(mw * 64 + 32 + l31) * IN_F + half * 8;

  for (int it = 0; it < 8; ++it) {
    const int g = kslice * 8 + it;
    const float sf = scales[sc_base + g];
    const int zw = qzeros[qz_base + (g >> 3)];
    const uint32_t z = (uint32_t)(zw >> ((g & 7) * 4)) & 0xFu;
    const uint32_t hz2u = 0x64006400u | z | (z << 16);
    const uint16_t hs = __builtin_bit_cast(uint16_t, __float2half(sf));
    const uint32_t s2u = (uint32_t)hs | ((uint32_t)hs << 16);
    uint4 q0 = *(const uint4*)(qweight + qw_base + it * 16);
    uint4 q1 = *(const uint4*)(qweight + qw_base + it * 16 + 4);

    if (it > 0) __syncthreads();
    const uint32_t w[8] = {q0.x, q0.y, q0.z, q0.w, q1.x, q1.y, q1.z, q1.w};
#pragma unroll
    for (int i = 0; i < 8; ++i) {
      uint4 v = dq_word(w[i], hz2u, s2u);
      *(uint4*)(&bT[bOff + (((wh * 4 + (i >> 1)) * 64 + (i & 1) * 32) * 8)]) = v;
    }
    __syncthreads();

#pragma unroll
    for (int ks = 0; ks < 8; ++ks) {
      const int ko = kbase + it * 128 + ks * 16;
      float4 f0 = *(const float4*)(xf32 + arow0 + ko);
      float4 f1 = *(const float4*)(xf32 + arow0 + ko + 4);
      half8 a0 = half8{(_Float16)f0.x, (_Float16)f0.y, (_Float16)f0.z, (_Float16)f0.w,
                       (_Float16)f1.x, (_Float16)f1.y, (_Float16)f1.z, (_Float16)f1.w};
      float4 g0 = *(const float4*)(xf32 + arow1 + ko);
      float4 g1 = *(const float4*)(xf32 + arow1 + ko + 4);
      half8 a1 = half8{(_Float16)g0.x, (_Float16)g0.y, (_Float16)g0.z, (_Float16)g0.w,
                       (_Float16)g1.x, (_Float16)g1.y, (_Float16)g1.z, (_Float16)g1.w};
      half8 b0 = *(const half8*)(&bT[((nw * 2) * 8 * 64 + ks * 64 + lane) * 8]);
      half8 b1 = *(const half8*)(&bT[((nw * 2 + 1) * 8 * 64 + ks * 64 + lane) * 8]);
      acc[0][0] = __builtin_amdgcn_mfma_f32_32x32x16_f16(a0, b0, acc[0][0], 0, 0, 0);
      acc[0][1] = __builtin_amdgcn_mfma_f32_32x32x16_f16(a0, b1, acc[0][1], 0, 0, 0);
      acc[1][0] = __builtin_amdgcn_mfma_f32_32x32x16_f16(a1, b0, acc[1][0], 0, 0, 0);
      acc[1][1] = __builtin_amdgcn_mfma_f32_32x32x16_f16(a1, b1, acc[1][1], 0, 0, 0);
    }
  }

  const int cn = n0 + nw * 64 + l31;
#pragma unroll
  for (int im = 0; im < 2; ++im)
#pragma unroll
    for (int in2 = 0; in2 < 2; ++in2)
#pragma unroll
      for (int reg = 0; reg < 16; ++reg) {
        int m = mw * 64 + im * 32 + (reg & 3) + 8 * (reg >> 2) + 4 * half;
        atomicAdd(out + (long long)m * OUT_F + cn + in2 * 32, acc[im][in2][reg]);
      }
}

extern "C" void kernel_launch(void* const* d_in, const int* in_sizes, int n_in,
                              void* d_out, int out_size, void* d_ws, size_t ws_size,
                              hipStream_t stream) {
  const float* x = (const float*)d_in[0];
  const int* qw = (const int*)d_in[1];
  const float* sc = (const float*)d_in[2];
  const int* qz = (const int*)d_in[3];
  const float* bias = (const float*)d_in[4];
  float* out = (float*)d_out;

  const size_t aT_bytes = (size_t)M_TOTAL * IN_F * sizeof(uint16_t);           // 2 MiB
  const size_t part_bytes = (size_t)KSPLIT * M_TOTAL * OUT_F * sizeof(float);  // 32 MiB
  uint16_t* aT = (uint16_t*)d_ws;
  float* part = (float*)((char*)d_ws + aT_bytes);

  if (ws_size >= aT_bytes + part_bytes) {
    prologue<<<(M_TOTAL * IN_F) / (256 * 8), 256, 0, stream>>>(x, aT);
    awq_fast<0><<<NTILES * KSPLIT, 512, 0, stream>>>(aT, qw, sc, qz, part, out);
    reduce_out<<<(M_TOTAL * OUT_F) / (256 * 4), 256, 0, stream>>>(part, bias, out);
  } else if (ws_size >= aT_bytes) {
    init_out<<<(M_TOTAL * OUT_F) / (256 * 4), 256, 0, stream>>>(bias, out);
    prologue<<<(M_TOTAL * IN_F) / (256 * 8), 256, 0, stream>>>(x, aT);
    awq_fast<1><<<NTILES * KSPLIT, 512, 0, stream>>>(aT, qw, sc, qz, nullptr, out);
  } else {
    init_out<<<(M_TOTAL * OUT_F) / (256 * 4), 256, 0, stream>>>(bias, out);
    awq_fallback<<<FB_NTILES * 8, 256, 0, stream>>>(x, qw, sc, qz, out);
  }
}